// Round 9
// baseline (915.425 us; speedup 1.0000x reference)
//
#include <hip/hip_runtime.h>

typedef int v4i __attribute__((ext_vector_type(4)));
typedef unsigned int u32x4 __attribute__((ext_vector_type(4)));

static constexpr int K_DIM = 4096;
static constexpr int BM = 128, BN = 256, BK = 64;

// ---------------- per-token dynamic quantization ----------------
__global__ __launch_bounds__(256) void quant_kernel(const float* __restrict__ x,
                                                    signed char* __restrict__ xq,
                                                    float* __restrict__ xs) {
    const int token = blockIdx.x;
    const float4* row = (const float4*)(x + (size_t)token * K_DIM);
    const int t = threadIdx.x;
    float4 v[4];
    float m = 0.f;
#pragma unroll
    for (int i = 0; i < 4; ++i) {
        v[i] = row[t * 4 + i];
        m = fmaxf(m, fabsf(v[i].x));
        m = fmaxf(m, fabsf(v[i].y));
        m = fmaxf(m, fabsf(v[i].z));
        m = fmaxf(m, fabsf(v[i].w));
    }
#pragma unroll
    for (int d = 32; d > 0; d >>= 1) m = fmaxf(m, __shfl_xor(m, d));
    __shared__ float red[4];
    if ((t & 63) == 0) red[t >> 6] = m;
    __syncthreads();
    const float am = fmaxf(fmaxf(red[0], red[1]), fmaxf(red[2], red[3]));
    const float s = fmaxf(am, 1e-8f) * (1.0f / 127.0f);
    const float inv = 127.0f / fmaxf(am, 1e-8f);

    int pk[4];
#pragma unroll
    for (int i = 0; i < 4; ++i) {
        int q0 = (int)fminf(127.f, fmaxf(-127.f, rintf(v[i].x * inv)));
        int q1 = (int)fminf(127.f, fmaxf(-127.f, rintf(v[i].y * inv)));
        int q2 = (int)fminf(127.f, fmaxf(-127.f, rintf(v[i].z * inv)));
        int q3 = (int)fminf(127.f, fmaxf(-127.f, rintf(v[i].w * inv)));
        pk[i] = (q0 & 255) | ((q1 & 255) << 8) | ((q2 & 255) << 16) | (q3 << 24);
    }
    ((int4*)(xq + (size_t)token * K_DIM))[t] = make_int4(pk[0], pk[1], pk[2], pk[3]);
    if (t == 0) xs[token] = s;
}

// ---------------- weight repack: int32 -> packed int8 ----------------
__global__ __launch_bounds__(256) void repack_kernel(const int* __restrict__ w32,
                                                     int4* __restrict__ w8,
                                                     int n16) {
    const int idx = blockIdx.x * 256 + threadIdx.x;
    if (idx >= n16) return;
    const int4* src = (const int4*)w32 + (size_t)idx * 4;
    int4 a = src[0], b = src[1], c = src[2], d = src[3];
    int p0 = (a.x & 255) | ((a.y & 255) << 8) | ((a.z & 255) << 16) | (a.w << 24);
    int p1 = (b.x & 255) | ((b.y & 255) << 8) | ((b.z & 255) << 16) | (b.w << 24);
    int p2 = (c.x & 255) | ((c.y & 255) << 8) | ((c.z & 255) << 16) | (c.w << 24);
    int p3 = (d.x & 255) | ((d.y & 255) << 8) | ((d.z & 255) << 16) | (d.w << 24);
    w8[idx] = make_int4(p0, p1, p2, p3);
}

// ---- A-frag direct load: buffer_load_dwordx4 with fixed voffset + scalar soffset
#define ISSUE_A(SET, SOFF)                                                           \
    {                                                                                \
        unsigned int so_ = (SOFF);                                                   \
        asm volatile("buffer_load_dwordx4 %0, %1, %2, %3 offen"                      \
                     : "=&v"(SET[0]) : "v"(voff0), "s"(srsrc), "s"(so_) : "memory"); \
        asm volatile("buffer_load_dwordx4 %0, %1, %2, %3 offen"                      \
                     : "=&v"(SET[1]) : "v"(voff1), "s"(srsrc), "s"(so_) : "memory"); \
        asm volatile("buffer_load_dwordx4 %0, %1, %2, %3 offen"                      \
                     : "=&v"(SET[2]) : "v"(voff2), "s"(srsrc), "s"(so_) : "memory"); \
        asm volatile("buffer_load_dwordx4 %0, %1, %2, %3 offen"                      \
                     : "=&v"(SET[3]) : "v"(voff3), "s"(srsrc), "s"(so_) : "memory"); \
    }

// ---- int8 MFMA GEMM: A direct global->reg (L1-served), B LDS-staged (verified
// ---- zero-conflict layout), 2-buf 32 KB LDS, counted vmcnt(6), R7 skeleton ----
__global__ __launch_bounds__(512, 4) void gemm_kernel(const signed char* __restrict__ xq,
                                                      const signed char* __restrict__ w8,
                                                      const float* __restrict__ xs,
                                                      const float* __restrict__ scale,
                                                      const float* __restrict__ bias,
                                                      float* __restrict__ out,
                                                      int N) {
    __shared__ __align__(16) signed char sB[2 * 16384];   // 2 bufs x 16 KB

    const int tid = threadIdx.x;
    const int lane = tid & 63;
    const int wid = tid >> 6;          // 8 waves: 2(M) x 4(N)
    const int wm = wid >> 2;
    const int wn = wid & 3;

    // T1: XCD-aware bijective swizzle (grid = 43 x 64 = 2752, divisible by 8)
    const int nwg = gridDim.x * gridDim.y;
    int flat = blockIdx.y * gridDim.x + blockIdx.x;
    if ((nwg & 7) == 0) flat = (flat & 7) * (nwg >> 3) + (flat >> 3);
    const int by = flat % gridDim.y;
    const int bx = flat / gridDim.y;
    const int m0 = by * BM;
    const int n0 = bx * BN;

    v4i acc[4][4];
    const v4i vzero = {0, 0, 0, 0};
#pragma unroll
    for (int i = 0; i < 4; ++i)
#pragma unroll
        for (int j = 0; j < 4; ++j) acc[i][j] = vzero;

    // ---- B staging (R7-verified; LDS dest linear, packed 128-B rows) ----
    const int srow = tid >> 3;
    const int s = (tid & 7) ^ (srow & 7);
    const signed char* srcB = w8 + ((size_t)n0 + srow + (s >> 2) * 128) * K_DIM + (s & 3) * 16;

    auto stageB = [&](int bufoff, int kb) {   // 2 issues: B rows 0-127 / 128-255 (packed)
        __builtin_amdgcn_global_load_lds(
            (const __attribute__((address_space(1))) void*)(srcB + kb),
            (__attribute__((address_space(3))) void*)&sB[bufoff + wid * 1024], 16, 0, 0);
        __builtin_amdgcn_global_load_lds(
            (const __attribute__((address_space(1))) void*)(srcB + (size_t)64 * K_DIM + kb),
            (__attribute__((address_space(3))) void*)&sB[bufoff + 8192 + wid * 1024], 16, 0, 0);
    };

    // ---- A direct-load descriptor + per-lane voffsets ----
    const signed char* pA = xq + (size_t)m0 * K_DIM;
    u32x4 srsrc;
    srsrc[0] = (unsigned int)(uintptr_t)pA;
    srsrc[1] = (unsigned int)((uintptr_t)pA >> 32);
    srsrc[2] = 0xFFFFFFFFu;           // num_records: disabled (addresses always in-bounds)
    srsrc[3] = 0x00020000u;
    const unsigned int arow = (unsigned int)(wm * 64 + (lane & 15)) * K_DIM + ((lane >> 4) << 4);
    const unsigned int voff0 = arow;
    const unsigned int voff1 = arow + 16 * K_DIM;
    const unsigned int voff2 = arow + 32 * K_DIM;
    const unsigned int voff3 = arow + 48 * K_DIM;

    // ---- B read constants (verified zero-conflict pattern) ----
    const int colB = (((wn >> 1) * 4 + (lane >> 4)) ^ (lane & 7)) << 4;
    const int rowB = ((wn & 1) * 64 + (lane & 15)) * 128;

    v4i aA[4], aB[4];

#define KMFMA(CUR)                                                             \
    {                                                                          \
        asm volatile("s_waitcnt lgkmcnt(0)" ::: "memory");                     \
        __builtin_amdgcn_s_setprio(1);                                         \
        _Pragma("unroll") for (int ni = 0; ni < 4; ++ni)                       \
            _Pragma("unroll") for (int mi = 0; mi < 4; ++mi)                   \
                acc[mi][ni] = __builtin_amdgcn_mfma_i32_16x16x64_i8(           \
                    CUR[mi], b_[ni], acc[mi][ni], 0, 0, 0);                    \
        __builtin_amdgcn_s_setprio(0);                                         \
    }
#define RDB(BUFOFF)                                                            \
    v4i b_[4];                                                                 \
    _Pragma("unroll") for (int ni = 0; ni < 4; ++ni)                           \
        b_[ni] = *(const v4i*)&sB[(BUFOFF) + rowB + ni * 2048 + colB];

    // ---- prologue: A(0)->aA, B(0)->buf0, A(1)->aB, B(1)->buf1; wait A(0)+B(0)
    ISSUE_A(aA, 0);
    stageB(0, 0);
    ISSUE_A(aB, BK);
    stageB(16384, BK);
    asm volatile("s_waitcnt vmcnt(6)" ::: "memory");
    __builtin_amdgcn_s_barrier();

    // ---- main loop: bodies kt=0..61 (2-unrolled; even uses aA/buf0, odd aB/buf1)
    unsigned int soff = 2 * BK;
    for (int kt = 0; kt < 62; kt += 2) {
        {   // even body: consume A(kt) in aA, b from buf0; issue A(kt+2)->aA; stage B(kt+2)->buf0
            RDB(0);
            KMFMA(aA);
            ISSUE_A(aA, soff);
            __builtin_amdgcn_s_barrier();               // all waves done reading buf0
            stageB(0, (int)soff);
            asm volatile("s_waitcnt vmcnt(6)" ::: "memory");   // A(kt+1)+B(kt+1) landed
            __builtin_amdgcn_s_barrier();               // publish buf1 = B(kt+1)
        }
        {   // odd body
            RDB(16384);
            KMFMA(aB);
            ISSUE_A(aB, soff + BK);
            __builtin_amdgcn_s_barrier();
            stageB(16384, (int)(soff + BK));
            asm volatile("s_waitcnt vmcnt(6)" ::: "memory");   // A(kt+2)+B(kt+2) landed
            __builtin_amdgcn_s_barrier();               // publish buf0 = B(kt+2)
        }
        soff += 2 * BK;
    }

    // ---- body 62 (buf0): no new issues; drain A(63)+B(63)
    {
        RDB(0);
        KMFMA(aA);
        asm volatile("s_waitcnt vmcnt(0)" ::: "memory");
        __builtin_amdgcn_s_barrier();                   // publish buf1 = B(63)
    }
    // ---- body 63 (buf1)
    {
        RDB(16384);
        KMFMA(aB);
    }

    // ---- output epilogue: D reg r of lane l -> row (l>>4)*4+r, col l&15 per frag
    const int mrow0 = m0 + wm * 64 + ((lane >> 4) << 2);
    const int ncol0 = n0 + wn * 64 + (lane & 15);
    float xsv[4][4];
#pragma unroll
    for (int mi = 0; mi < 4; ++mi)
#pragma unroll
        for (int r = 0; r < 4; ++r) xsv[mi][r] = xs[mrow0 + mi * 16 + r];

#pragma unroll
    for (int ni = 0; ni < 4; ++ni) {
        const int n = ncol0 + ni * 16;
        const float sc = scale[n];
        const float bs = bias[n];
#pragma unroll
        for (int mi = 0; mi < 4; ++mi) {
#pragma unroll
            for (int r = 0; r < 4; ++r) {
                const int m = mrow0 + mi * 16 + r;
                out[(size_t)m * N + n] = (float)acc[mi][ni][r] * xsv[mi][r] * sc + bs;
            }
        }
    }
}

extern "C" void kernel_launch(void* const* d_in, const int* in_sizes, int n_in,
                              void* d_out, int out_size, void* d_ws, size_t ws_size,
                              hipStream_t stream) {
    const float* x     = (const float*)d_in[0];
    const int*   w32   = (const int*)d_in[1];
    const float* scale = (const float*)d_in[2];
    const float* bias  = (const float*)d_in[3];
    float* out = (float*)d_out;

    const int M = in_sizes[0] / K_DIM;   // 8192
    const int N = in_sizes[2];           // 11008

    char* ws = (char*)d_ws;
    signed char* xq = (signed char*)ws;                                  // M*K
    float* xs = (float*)(ws + (size_t)M * K_DIM);                        // M floats
    signed char* w8 = (signed char*)(ws + (size_t)M * K_DIM + (size_t)M * sizeof(float));  // N*K

    quant_kernel<<<M, 256, 0, stream>>>(x, xq, xs);

    const int n16 = (N * K_DIM) / 16;
    repack_kernel<<<(n16 + 255) / 256, 256, 0, stream>>>(w32, (int4*)w8, n16);

    gemm_kernel<<<dim3(N / BN, M / BM), 512, 0, stream>>>(xq, w8, xs, scale, bias, out, N);
}

// Round 10
// 562.677 us; speedup vs baseline: 1.6269x; 1.6269x over previous
//
#include <hip/hip_runtime.h>

typedef int v4i __attribute__((ext_vector_type(4)));

static constexpr int K_DIM = 4096;
static constexpr int BM = 128, BN = 256, BK = 64;

// ---------------- per-token dynamic quantization ----------------
__global__ __launch_bounds__(256) void quant_kernel(const float* __restrict__ x,
                                                    signed char* __restrict__ xq,
                                                    float* __restrict__ xs) {
    const int token = blockIdx.x;
    const float4* row = (const float4*)(x + (size_t)token * K_DIM);
    const int t = threadIdx.x;
    float4 v[4];
    float m = 0.f;
#pragma unroll
    for (int i = 0; i < 4; ++i) {
        v[i] = row[t * 4 + i];
        m = fmaxf(m, fabsf(v[i].x));
        m = fmaxf(m, fabsf(v[i].y));
        m = fmaxf(m, fabsf(v[i].z));
        m = fmaxf(m, fabsf(v[i].w));
    }
#pragma unroll
    for (int d = 32; d > 0; d >>= 1) m = fmaxf(m, __shfl_xor(m, d));
    __shared__ float red[4];
    if ((t & 63) == 0) red[t >> 6] = m;
    __syncthreads();
    const float am = fmaxf(fmaxf(red[0], red[1]), fmaxf(red[2], red[3]));
    const float s = fmaxf(am, 1e-8f) * (1.0f / 127.0f);
    const float inv = 127.0f / fmaxf(am, 1e-8f);

    int pk[4];
#pragma unroll
    for (int i = 0; i < 4; ++i) {
        int q0 = (int)fminf(127.f, fmaxf(-127.f, rintf(v[i].x * inv)));
        int q1 = (int)fminf(127.f, fmaxf(-127.f, rintf(v[i].y * inv)));
        int q2 = (int)fminf(127.f, fmaxf(-127.f, rintf(v[i].z * inv)));
        int q3 = (int)fminf(127.f, fmaxf(-127.f, rintf(v[i].w * inv)));
        pk[i] = (q0 & 255) | ((q1 & 255) << 8) | ((q2 & 255) << 16) | (q3 << 24);
    }
    ((int4*)(xq + (size_t)token * K_DIM))[t] = make_int4(pk[0], pk[1], pk[2], pk[3]);
    if (t == 0) xs[token] = s;
}

// ---------------- weight repack: int32 -> packed int8 ----------------
__global__ __launch_bounds__(256) void repack_kernel(const int* __restrict__ w32,
                                                     int4* __restrict__ w8,
                                                     int n16) {
    const int idx = blockIdx.x * 256 + threadIdx.x;
    if (idx >= n16) return;
    const int4* src = (const int4*)w32 + (size_t)idx * 4;
    int4 a = src[0], b = src[1], c = src[2], d = src[3];
    int p0 = (a.x & 255) | ((a.y & 255) << 8) | ((a.z & 255) << 16) | (a.w << 24);
    int p1 = (b.x & 255) | ((b.y & 255) << 8) | ((b.z & 255) << 16) | (b.w << 24);
    int p2 = (c.x & 255) | ((c.y & 255) << 8) | ((c.z & 255) << 16) | (c.w << 24);
    int p3 = (d.x & 255) | ((d.y & 255) << 8) | ((d.z & 255) << 16) | (d.w << 24);
    w8[idx] = make_int4(p0, p1, p2, p3);
}

// ---- int8 MFMA GEMM: R7 base (128x256 tile, BK=64 packed 128-B LDS rows,
// ---- verified zero-conflict) with 3-buffer LDS: verify distance 1 -> 2 bodies.
// ---- Static buffer offsets via 3-body unroll; 72 KB LDS -> 2 blocks/CU. ----
__global__ __launch_bounds__(512, 4) void gemm_kernel(const signed char* __restrict__ xq,
                                                      const signed char* __restrict__ w8,
                                                      const float* __restrict__ xs,
                                                      const float* __restrict__ scale,
                                                      const float* __restrict__ bias,
                                                      float* __restrict__ out,
                                                      int N) {
    __shared__ __align__(16) signed char sA[3 * 8192];    // 3 bufs x 8 KB
    __shared__ __align__(16) signed char sB[3 * 16384];   // 3 bufs x 16 KB

    const int tid = threadIdx.x;
    const int lane = tid & 63;
    const int wid = tid >> 6;          // 8 waves: 2(M) x 4(N)
    const int wm = wid >> 2;
    const int wn = wid & 3;

    // T1: XCD-aware bijective swizzle (grid = 43 x 64 = 2752, divisible by 8)
    const int nwg = gridDim.x * gridDim.y;
    int flat = blockIdx.y * gridDim.x + blockIdx.x;
    if ((nwg & 7) == 0) flat = (flat & 7) * (nwg >> 3) + (flat >> 3);
    const int by = flat % gridDim.y;          // M fast within chunk -> B panel L2-resident
    const int bx = flat / gridDim.y;
    const int m0 = by * BM;
    const int n0 = bx * BN;

    v4i acc[4][4];
    const v4i vzero = {0, 0, 0, 0};
#pragma unroll
    for (int i = 0; i < 4; ++i)
#pragma unroll
        for (int j = 0; j < 4; ++j) acc[i][j] = vzero;

    // ---- staging sources (R7-verified; LDS dest linear, wave-uniform base) ----
    const int srow = tid >> 3;
    const int s = (tid & 7) ^ (srow & 7);
    const signed char* srcA = xq + ((size_t)m0 + srow + (s >> 2) * 64) * K_DIM + (s & 3) * 16;
    const signed char* srcB = w8 + ((size_t)n0 + srow + (s >> 2) * 128) * K_DIM + (s & 3) * 16;

    auto stage = [&](int offA, int offB, unsigned int kb) {   // 3 issues: A, B-lo, B-hi
        __builtin_amdgcn_global_load_lds(
            (const __attribute__((address_space(1))) void*)(srcA + kb),
            (__attribute__((address_space(3))) void*)&sA[offA + wid * 1024], 16, 0, 0);
        __builtin_amdgcn_global_load_lds(
            (const __attribute__((address_space(1))) void*)(srcB + kb),
            (__attribute__((address_space(3))) void*)&sB[offB + wid * 1024], 16, 0, 0);
        __builtin_amdgcn_global_load_lds(
            (const __attribute__((address_space(1))) void*)(srcB + (size_t)64 * K_DIM + kb),
            (__attribute__((address_space(3))) void*)&sB[offB + 8192 + wid * 1024], 16, 0, 0);
    };

    // ---- read-side per-lane constants (R7-verified zero-conflict) ----
    const int colA = ((wm * 4 + (lane >> 4)) ^ (lane & 7)) << 4;
    const int colB = (((wn >> 1) * 4 + (lane >> 4)) ^ (lane & 7)) << 4;
    const int rowA = (lane & 15) * 128;
    const int rowB = ((wn & 1) * 64 + (lane & 15)) * 128;

    // One body: read frags, MFMA, barrier, [stage tile into the just-read bufs],
    // counted vmcnt (distance-2 verify), barrier.
#define BODY(OA, OB, DOSTAGE, KB, VMSTR)                                       \
    {                                                                          \
        v4i a_[4], b_[4];                                                      \
        _Pragma("unroll") for (int mi = 0; mi < 4; ++mi)                       \
            a_[mi] = *(const v4i*)&sA[(OA) + rowA + mi * 2048 + colA];         \
        _Pragma("unroll") for (int ni = 0; ni < 4; ++ni)                       \
            b_[ni] = *(const v4i*)&sB[(OB) + rowB + ni * 2048 + colB];         \
        __builtin_amdgcn_s_setprio(1);                                         \
        _Pragma("unroll") for (int mi = 0; mi < 4; ++mi)                       \
            _Pragma("unroll") for (int ni = 0; ni < 4; ++ni)                   \
                acc[mi][ni] = __builtin_amdgcn_mfma_i32_16x16x64_i8(           \
                    a_[mi], b_[ni], acc[mi][ni], 0, 0, 0);                     \
        __builtin_amdgcn_s_setprio(0);                                         \
        __builtin_amdgcn_s_barrier();                                          \
        if (DOSTAGE) stage((OA), (OB), (KB));                                  \
        asm volatile("s_waitcnt vmcnt(" VMSTR ")" ::: "memory");               \
        __builtin_amdgcn_s_barrier();                                          \
    }

    // ---- prologue: stage tiles 0,1,2 into bufs 0,1,2; publish tile 0 ----
    stage(0, 0, 0);
    stage(8192, 16384, BK);
    stage(16384, 32768, 2 * BK);
    asm volatile("s_waitcnt vmcnt(6)" ::: "memory");   // tile 0 landed
    __builtin_amdgcn_s_barrier();

    // ---- main loop: bodies 0..59 (20 x 3, static offsets) ----
    unsigned int kb = 3 * BK;   // byte offset of tile being staged this body
    for (int it = 0; it < 20; ++it) {
        BODY(0,     0,     1, kb,          "6");   // body 3it+0: reads buf0
        BODY(8192,  16384, 1, kb + BK,     "6");   // body 3it+1: reads buf1
        BODY(16384, 32768, 1, kb + 2 * BK, "6");   // body 3it+2: reads buf2
        kb += 3 * BK;
    }

    // ---- tail: bodies 60..62 (stage 63 at body 60; waits 6/3/0), body 63 pure ----
    BODY(0,     0,     1, (unsigned int)(63 * BK), "6");   // body 60
    BODY(8192,  16384, 0, 0u,                      "3");   // body 61
    BODY(16384, 32768, 0, 0u,                      "0");   // body 62
    {   // body 63: reads buf0 (tile 63), MFMA only
        v4i a_[4], b_[4];
#pragma unroll
        for (int mi = 0; mi < 4; ++mi)
            a_[mi] = *(const v4i*)&sA[0 + rowA + mi * 2048 + colA];
#pragma unroll
        for (int ni = 0; ni < 4; ++ni)
            b_[ni] = *(const v4i*)&sB[0 + rowB + ni * 2048 + colB];
        __builtin_amdgcn_s_setprio(1);
#pragma unroll
        for (int mi = 0; mi < 4; ++mi)
#pragma unroll
            for (int ni = 0; ni < 4; ++ni)
                acc[mi][ni] = __builtin_amdgcn_mfma_i32_16x16x64_i8(
                    a_[mi], b_[ni], acc[mi][ni], 0, 0, 0);
        __builtin_amdgcn_s_setprio(0);
    }
#undef BODY

    // ---- output epilogue: D reg r of lane l -> row (l>>4)*4+r, col l&15 per frag
    const int mrow0 = m0 + wm * 64 + ((lane >> 4) << 2);
    const int ncol0 = n0 + wn * 64 + (lane & 15);
    float xsv[4][4];
#pragma unroll
    for (int mi = 0; mi < 4; ++mi)
#pragma unroll
        for (int r = 0; r < 4; ++r) xsv[mi][r] = xs[mrow0 + mi * 16 + r];

#pragma unroll
    for (int ni = 0; ni < 4; ++ni) {
        const int n = ncol0 + ni * 16;
        const float sc = scale[n];
        const float bs = bias[n];
#pragma unroll
        for (int mi = 0; mi < 4; ++mi) {
#pragma unroll
            for (int r = 0; r < 4; ++r) {
                const int m = mrow0 + mi * 16 + r;
                out[(size_t)m * N + n] = (float)acc[mi][ni][r] * xsv[mi][r] * sc + bs;
            }
        }
    }
}

extern "C" void kernel_launch(void* const* d_in, const int* in_sizes, int n_in,
                              void* d_out, int out_size, void* d_ws, size_t ws_size,
                              hipStream_t stream) {
    const float* x     = (const float*)d_in[0];
    const int*   w32   = (const int*)d_in[1];
    const float* scale = (const float*)d_in[2];
    const float* bias  = (const float*)d_in[3];
    float* out = (float*)d_out;

    const int M = in_sizes[0] / K_DIM;   // 8192
    const int N = in_sizes[2];           // 11008

    char* ws = (char*)d_ws;
    signed char* xq = (signed char*)ws;                                  // M*K
    float* xs = (float*)(ws + (size_t)M * K_DIM);                        // M floats
    signed char* w8 = (signed char*)(ws + (size_t)M * K_DIM + (size_t)M * sizeof(float));  // N*K

    quant_kernel<<<M, 256, 0, stream>>>(x, xq, xs);

    const int n16 = (N * K_DIM) / 16;
    repack_kernel<<<(n16 + 255) / 256, 256, 0, stream>>>(w32, (int4*)w8, n16);

    gemm_kernel<<<dim3(N / BN, M / BM), 512, 0, stream>>>(xq, w8, xs, scale, bias, out, N);
}